// Round 9
// baseline (271.260 us; speedup 1.0000x reference)
//
#include <hip/hip_runtime.h>

#define NN 200000      // nodes; D=128 features, 40 classes (padded to 48 in wt)
#define NW 12          // waves per block (768 threads -> allocator grants 84 VGPR)
#define NBLK 256       // persistent blocks (1 per CU; LDS pins 1 block/CU)
#define NT 12500       // tiles of 16 rows: 12500*16 = NN exactly
#define WSTRIDE (NBLK * NW)   // 3072 global waves

typedef __attribute__((ext_vector_type(8))) short bf16x8;
typedef __attribute__((ext_vector_type(4))) float f32x4;
typedef __attribute__((ext_vector_type(4))) unsigned int u32x4;

// round-to-nearest-even fp32 -> bf16 bits (prep kernel only)
static __device__ __forceinline__ short f2bf(float f) {
    unsigned u = __builtin_bit_cast(unsigned, f);
    u += 0x7fffu + ((u >> 16) & 1u);
    return (short)(u >> 16);
}

// pack 2 floats -> 2 bf16 in one u32 (round-half-up)
static __device__ __forceinline__ unsigned pk2(float a, float b) {
    unsigned ua = __builtin_bit_cast(unsigned, a) + 0x8000u;
    unsigned ub = __builtin_bit_cast(unsigned, b) + 0x8000u;
    return __builtin_amdgcn_perm(ub, ua, 0x07060302u);
}

// XOR-swizzled LDS offset for element (r, k) of a [*,128] bf16 table.
// 16B chunks xored with (r&15) -> conflict-free ds_read_b128 fragments.
static __device__ __forceinline__ int swz(int r, int k) {
    return (r << 7) + (((k >> 3) ^ (r & 15)) << 3) + (k & 7);
}

// Pre-transpose + bf16-convert weights into workspace (elements):
// [0) Wt0[n][k]=W0[k][n] 128x128 | [16384) Wt1 | [32768) Wt2 | [49152) Wt3 48x128 (n>=40 zero)
__global__ void prep_weights_k(const float* __restrict__ W0, const float* __restrict__ W1,
                               const float* __restrict__ W2, const float* __restrict__ W3,
                               short* __restrict__ wt) {
    int e = blockIdx.x * 256 + threadIdx.x;   // 216 blocks * 256 = 55296
    if (e < 49152) {
        int l = e >> 14;
        int i = e & 16383;
        int n = i >> 7, k = i & 127;
        const float* W = (l == 0) ? W0 : ((l == 1) ? W1 : W2);
        wt[e] = f2bf(W[(k << 7) + n]);
    } else if (e < 55296) {
        int i = e - 49152;
        int n = i >> 7, k = i & 127;
        wt[e] = (n < 40) ? f2bf(W3[k * 40 + n]) : (short)0;
    }
}

// Persistent fused 4-layer MLP + log_softmax. R6 base (768 thr / 12 waves /
// 84 VGPR / loop-carried x prefetch / all weights + biases in LDS) plus:
//  - SOFTWARE-PIPELINED epilogue<->dense: dense k-slice ks only needs
//    epilogue columns 2ks,2ks+1, so each layer boundary is 4 slices of
//    {epi(2ks), epi(2ks+1), A-read(ks), 8 MFMA}. Ping-pong accumulators
//    (accA/accB) make old-acc SiLU VALU independent of new-acc MFMA ->
//    compiler co-schedules; the serial trans-heavy epilogue (~700cy/layer)
//    overlaps the dense LDS+MFMA phase. Peak live ~78 regs < 84 grant.
//  - biases folded into acc INIT (acc = bias, not zero+add): -96 VALU/tile.
//  - x prefetch issued mid-way through the epi2/L3 loop (acc half-dead):
//    cover = half L3 + softmax ~900cy.
// LDS = 110592 (sW) + 49152 (sA) + 1536 (sB) = 161280 <= 163840 -> 1 block/CU.
__global__ __launch_bounds__(768) __attribute__((amdgpu_waves_per_eu(3, 3)))
void mlp_fused_k(const float* __restrict__ x, const short* __restrict__ wt,
                 const float* __restrict__ b0, const float* __restrict__ b1,
                 const float* __restrict__ b2, const float* __restrict__ b3,
                 float* __restrict__ out) {
    __shared__ __align__(16) short sW[55296];       // all 4 layers, swizzled
    __shared__ __align__(16) short sA[NW][2048];    // per-wave activation slices
    __shared__ __align__(16) float sB[384];         // b0|b1|b2

    const int tid  = (int)threadIdx.x;
    const int lane = tid & 63;
    const int wv   = tid >> 6;       // wave 0..11
    const int m    = lane & 15;      // row (A) / col (B,C) within 16-tile
    const int quad = lane >> 4;      // 0..3
    short* sAw = &sA[wv][0];

    // ---- stage ALL weights global->LDS (swizzled), 6912 16B chunks = 9*768 ----
    {
        const u32x4* src = (const u32x4*)wt;
        #pragma unroll
        for (int i = 0; i < 9; ++i) {
            int q = tid + i * 768;             // exactly 6912 total, no tail
            int R = q >> 4, c = q & 15;
            *(u32x4*)&sW[(R << 7) + ((c ^ (R & 15)) << 3)] = src[q];
        }
        if (tid < 384)
            sB[tid] = (tid < 128) ? b0[tid] : (tid < 256) ? b1[tid - 128] : b2[tid - 256];
    }
    __syncthreads();   // the ONLY barrier

    // layer-3 bias: only 3 regs, fine to hoist
    const bool val2 = (m < 8);
    const float b3v0 = b3[m], b3v1 = b3[16 + m], b3v2 = val2 ? b3[32 + m] : 0.f;

    f32x4 accA[8], accB[8];

    // acc init = bias(lyr) from LDS (bias folded into MFMA C-input)
    auto initb = [&](f32x4* a, int lyr) {
        #pragma unroll
        for (int ct = 0; ct < 8; ++ct) {
            float bb = sB[(lyr << 7) + (ct << 4) + m];
            #pragma unroll
            for (int r = 0; r < 4; ++r) a[ct][r] = bb;
        }
    };

    // SiLU + bf16 -> sAw for ONE ct column-group (4 elems)
    auto epi_ct = [&](const f32x4* a, int ct) {
        #pragma unroll
        for (int r = 0; r < 4; ++r) {
            float v = a[ct][r];
            float h = v * __builtin_amdgcn_rcpf(1.f + __expf(-v));
            int rl = (quad << 2) + r;                // C/D: row = quad*4+reg
            unsigned u = __builtin_bit_cast(unsigned, h) + 0x8000u;
            sAw[swz(rl, (ct << 4) + m)] = (short)(u >> 16);
        }
    };

    // one dense k-slice: A-frag(ks) from sAw (cols 2ks,2ks+1 just written), 8 MFMA
    auto dense_ks = [&](f32x4* a, int lbase, int ks) {
        int kk = (ks << 5) + (quad << 3);
        bf16x8 a0 = *(const bf16x8*)&sAw[swz(m, kk)];
        __builtin_amdgcn_s_setprio(1);
        #pragma unroll
        for (int ct = 0; ct < 8; ++ct) {
            bf16x8 b = *(const bf16x8*)&sW[lbase + swz((ct << 4) + m, kk)];
            a[ct] = __builtin_amdgcn_mfma_f32_16x16x32_bf16(a0, b, a[ct], 0, 0, 0);
        }
        __builtin_amdgcn_s_setprio(0);
    };

    // one layer-3 k-slice: A-frag(ks), 3 MFMA into c3
    auto l3_ks = [&](f32x4* c3, int ks) {
        int kk = (ks << 5) + (quad << 3);
        bf16x8 a0 = *(const bf16x8*)&sAw[swz(m, kk)];
        __builtin_amdgcn_s_setprio(1);
        #pragma unroll
        for (int ct = 0; ct < 3; ++ct) {
            bf16x8 b = *(const bf16x8*)&sW[49152 + swz((ct << 4) + m, kk)];
            c3[ct] = __builtin_amdgcn_mfma_f32_16x16x32_bf16(a0, b, c3[ct], 0, 0, 0);
        }
        __builtin_amdgcn_s_setprio(0);
    };

    // ---- persistent tile loop; x loads one tile deep (loop-carried raw) ----
    int t = (int)blockIdx.x * NW + wv;       // first tile for this wave (< WSTRIDE)
    f32x4 raw[8];
    {
        const f32x4* p = (const f32x4*)(x + ((long)(t * 16 + m) << 7)) + quad * 2;
        #pragma unroll
        for (int ks = 0; ks < 4; ++ks) { raw[ks * 2] = p[ks * 8]; raw[ks * 2 + 1] = p[ks * 8 + 1]; }
    }

    while (true) {
        // pack x for CURRENT tile (loads issued last iteration / prologue)
        u32x4 xp[4];
        #pragma unroll
        for (int ks = 0; ks < 4; ++ks) {
            f32x4 va = raw[ks * 2], vb = raw[ks * 2 + 1];
            u32x4 ua;
            ua[0] = pk2(va[0], va[1]); ua[1] = pk2(va[2], va[3]);
            ua[2] = pk2(vb[0], vb[1]); ua[3] = pk2(vb[2], vb[3]);
            xp[ks] = ua;
        }

        // layer 0 -> accA (acc init = bias0); A from packed regs
        initb(accA, 0);
        __builtin_amdgcn_s_setprio(1);
        #pragma unroll
        for (int ks = 0; ks < 4; ++ks) {
            bf16x8 a0 = __builtin_bit_cast(bf16x8, xp[ks]);
            int kk = (ks << 5) + (quad << 3);
            #pragma unroll
            for (int ct = 0; ct < 8; ++ct) {
                bf16x8 b = *(const bf16x8*)&sW[swz((ct << 4) + m, kk)];
                accA[ct] = __builtin_amdgcn_mfma_f32_16x16x32_bf16(a0, b, accA[ct], 0, 0, 0);
            }
        }
        __builtin_amdgcn_s_setprio(0);

        // epi0 (accA) interleaved with dense1 -> accB
        initb(accB, 1);
        #pragma unroll
        for (int ks = 0; ks < 4; ++ks) {
            epi_ct(accA, 2 * ks);
            epi_ct(accA, 2 * ks + 1);
            dense_ks(accB, 16384, ks);
        }

        // epi1 (accB) interleaved with dense2 -> accA
        initb(accA, 2);
        #pragma unroll
        for (int ks = 0; ks < 4; ++ks) {
            epi_ct(accB, 2 * ks);
            epi_ct(accB, 2 * ks + 1);
            dense_ks(accA, 32768, ks);
        }

        int tn = t + WSTRIDE;
        bool has = tn < NT;                   // wave-uniform

        // epi2 (accA) interleaved with layer 3 -> c3; x prefetch issued midway
        f32x4 c3[3];
        #pragma unroll
        for (int r = 0; r < 4; ++r) { c3[0][r] = b3v0; c3[1][r] = b3v1; c3[2][r] = b3v2; }
        #pragma unroll
        for (int ks = 0; ks < 2; ++ks) {
            epi_ct(accA, 2 * ks);
            epi_ct(accA, 2 * ks + 1);
            l3_ks(c3, ks);
        }
        if (has) {   // accA half-dead: 16 + c3 12 + raw 32 + temps ~= 74 regs
            const f32x4* p = (const f32x4*)(x + ((long)(tn * 16 + m) << 7)) + quad * 2;
            #pragma unroll
            for (int ks = 0; ks < 4; ++ks) { raw[ks * 2] = p[ks * 8]; raw[ks * 2 + 1] = p[ks * 8 + 1]; }
        }
        #pragma unroll
        for (int ks = 2; ks < 4; ++ks) {
            epi_ct(accA, 2 * ks);
            epi_ct(accA, 2 * ks + 1);
            l3_ks(c3, ks);
        }

        // log_softmax over 40 cols + store
        #pragma unroll
        for (int r = 0; r < 4; ++r) {
            float v0 = c3[0][r];
            float v1 = c3[1][r];
            float v2 = c3[2][r];
            float mx = fmaxf(v0, v1);
            mx = val2 ? fmaxf(mx, v2) : mx;
            #pragma unroll
            for (int s = 1; s < 16; s <<= 1)
                mx = fmaxf(mx, __shfl_xor(mx, s, 64));
            float sm = __expf(v0 - mx) + __expf(v1 - mx) + (val2 ? __expf(v2 - mx) : 0.f);
            #pragma unroll
            for (int s = 1; s < 16; s <<= 1)
                sm += __shfl_xor(sm, s, 64);
            float L = mx + __logf(sm);
            int grow = t * 16 + (quad << 2) + r;   // C/D: row = quad*4+reg
            float* orow = out + (long)grow * 40;
            orow[m]      = v0 - L;
            orow[16 + m] = v1 - L;
            if (val2) orow[32 + m] = v2 - L;
        }

        if (!has) break;
        t = tn;
    }
}

extern "C" void kernel_launch(void* const* d_in, const int* in_sizes, int n_in,
                              void* d_out, int out_size, void* d_ws, size_t ws_size,
                              hipStream_t stream) {
    const float* x   = (const float*)d_in[0];
    // d_in[1] = edge_index (unused: ChebConv K=1 ignores the Laplacian)
    const float* W0  = (const float*)d_in[2];
    const float* bb0 = (const float*)d_in[3];
    const float* W1  = (const float*)d_in[4];
    const float* bb1 = (const float*)d_in[5];
    const float* W2  = (const float*)d_in[6];
    const float* bb2 = (const float*)d_in[7];
    const float* W3  = (const float*)d_in[8];
    const float* bb3 = (const float*)d_in[9];
    short* wt  = (short*)d_ws;         // 110592 B of bf16 transposed weights
    float* out = (float*)d_out;

    hipLaunchKernelGGL(prep_weights_k, dim3(216), dim3(256), 0, stream, W0, W1, W2, W3, wt);
    hipLaunchKernelGGL(mlp_fused_k, dim3(NBLK), dim3(768), 0, stream,
                       x, wt, bb0, bb1, bb2, bb3, out);
}